// Round 6
// baseline (6283.313 us; speedup 1.0000x reference)
//
#include <hip/hip_runtime.h>
#include <cstdint>
#include <cstddef>

#define WIDTH 4096
#define DEPTH 512
#define NHIST 20
#define NWG 256
#define NTHR 1024
#define NGRP 128   // WGs per row-half sync group

typedef __attribute__((ext_vector_type(4))) float f32x4;
typedef __attribute__((ext_vector_type(8))) short bf16x8;

__device__ __forceinline__ ushort f2bf(float f) {
    uint32_t u = __float_as_uint(f);
    u += 0x7FFFu + ((u >> 16) & 1u);   // round-to-nearest-even
    return (ushort)(u >> 16);
}

// cur blocked layout: element (m, c): kv=c>>3, unit = ((kv>>2)*4 + (m>>4))*64
//   + (kv&3)*16 + (m&15); ushort offset = unit*8 + (c&7).
// -> wave-w fragment f = kc*4+mb occupies ushort offset w*16384 + f*512 +
//    (lq*16+lrow)*8: one contiguous 1KB burst per load instruction.

// ---------------- curr0 = tile(x) ------------------------------------------
__global__ __launch_bounds__(256) void init_curr_kernel(const float* __restrict__ x,
                                                        ushort* __restrict__ cur) {
    int g = blockIdx.x * 256 + threadIdx.x;   // 0..32767
    int kv = g >> 6, m = g & 63;
    int unit = ((kv >> 2) * 4 + (m >> 4)) * 64 + (kv & 3) * 16 + (m & 15);
    ushort4 lo, hi;
    lo.x = f2bf(x[kv * 8 + 0]); lo.y = f2bf(x[kv * 8 + 1]);
    lo.z = f2bf(x[kv * 8 + 2]); lo.w = f2bf(x[kv * 8 + 3]);
    hi.x = f2bf(x[kv * 8 + 4]); hi.y = f2bf(x[kv * 8 + 5]);
    hi.z = f2bf(x[kv * 8 + 6]); hi.w = f2bf(x[kv * 8 + 7]);
    ushort* dst = cur + (size_t)unit * 8;
    *(ushort4*)dst = lo;
    *(ushort4*)(dst + 4) = hi;
}

// ---------------- zero flags/counters ---------------------------------------
__global__ __launch_bounds__(256) void zero_flags_kernel(int* __restrict__ flags) {
    flags[blockIdx.x * 256 + threadIdx.x] = 0;   // grid 32 -> 8192 ints
}

// ---------------- bias GEMM, fp32 vector ALU --------------------------------
__global__ __launch_bounds__(256) void bias_gemm_kernel(const float* __restrict__ A,
                                                        const float* __restrict__ B,
                                                        float* __restrict__ C) {
    __shared__ float As[64][36];
    __shared__ float Bs[64][36];
    const int bm = blockIdx.y;
    const int bn = blockIdx.x;
    const int t  = threadIdx.x;
    const int tx = t & 15, ty = t >> 4;
    const int lr = t >> 3;
    const int lc = (t & 7) * 4;

    float acc[4][4] = {};
    for (int k0 = 0; k0 < WIDTH; k0 += 32) {
        float4 a0 = *(const float4*)&A[(size_t)(bm * 64 + lr) * WIDTH + k0 + lc];
        float4 a1 = *(const float4*)&A[(size_t)(bm * 64 + lr + 32) * WIDTH + k0 + lc];
        float4 b0 = *(const float4*)&B[(size_t)(bn * 64 + lr) * WIDTH + k0 + lc];
        float4 b1 = *(const float4*)&B[(size_t)(bn * 64 + lr + 32) * WIDTH + k0 + lc];
        __syncthreads();
        *(float4*)&As[lr][lc] = a0;  *(float4*)&As[lr + 32][lc] = a1;
        *(float4*)&Bs[lr][lc] = b0;  *(float4*)&Bs[lr + 32][lc] = b1;
        __syncthreads();
        #pragma unroll
        for (int k = 0; k < 32; k += 4) {
            float4 av[4], bv[4];
            #pragma unroll
            for (int mi = 0; mi < 4; mi++) av[mi] = *(const float4*)&As[ty * 4 + mi][k];
            #pragma unroll
            for (int ni = 0; ni < 4; ni++) bv[ni] = *(const float4*)&Bs[tx * 4 + ni][k];
            #pragma unroll
            for (int mi = 0; mi < 4; mi++)
                #pragma unroll
                for (int ni = 0; ni < 4; ni++)
                    acc[mi][ni] += av[mi].x * bv[ni].x + av[mi].y * bv[ni].y +
                                   av[mi].z * bv[ni].z + av[mi].w * bv[ni].w;
        }
    }
    #pragma unroll
    for (int mi = 0; mi < 4; mi++) {
        float4 v = make_float4(acc[mi][0], acc[mi][1], acc[mi][2], acc[mi][3]);
        *(float4*)&C[(size_t)(bm * 64 + ty * 4 + mi) * WIDTH + bn * 64 + tx * 4] = v;
    }
}

// ---------------- persistent reservoir: 256 WGs x 1024 thr ------------------
// 32x32 output tile per WG: WG t owns cols [(t>>1)*32, +32), rows (t&1)*32..+32.
// Rows are independent recurrences -> halves (t&1) are disjoint sync domains.
// Barrier v6: LAST-ARRIVER PUBLISHES. Each WG does one fetch_add(ACQ_REL) on
// its half's counter line (no readers on that line -- r2's regression was
// pollers sharing the RMW line); the WG seeing old==128*(d+1)-1 release-stores
// the half's gflag (separate line). tid0 pollers on gflag (128/line, r1/r5-
// verified pattern). Chain: drain -> add -> publish/notice = 3 LLC hops vs
// r1's 5 (store, collector-visible, sweep, publish, notice).
__global__ __launch_bounds__(NTHR, 4) void reservoir_kernel(
    const float* __restrict__ W,
    const float* __restrict__ scales,
    const float* __restrict__ b,      // [512][4096] fp32
    float* __restrict__ out,          // [64][20][4096] fp32
    ushort* __restrict__ cur0,
    ushort* __restrict__ cur1,
    int* __restrict__ flags)          // ctr[half] at +half*1024; gflag[half] at +2048+half*1024
{
    // partial: [wave16][col32][row32] fp32, XOR-swizzled rows:
    //   float idx = w*1024 + c*32 + (r ^ ((c&7)<<2))  -> conflict-free b128
    __shared__ float partial[16 * 32 * 32];   // 64 KB
    __shared__ float vals[32 * 33];           // [col][row] padded 33

    const int tid  = threadIdx.x;
    const int w    = tid >> 6;
    const int lane = tid & 63;
    const int lrow = lane & 15;
    const int lq   = lane >> 4;
    const int t    = blockIdx.x;
    const int half = t & 1;
    const int c0   = (t >> 1) * 32;   // global col base
    const int r0   = half * 32;       // global row (scale) base
    const int mb0  = half * 2;        // m-block base in blocked state layout
    int* ctr   = flags + half * 1024;          // RMW line: adds only, no readers
    int* gflag = flags + 2048 + half * 1024;   // broadcast line: 1 write/step, 128 pollers

    // epilogue mapping: thread -> (local col ecol, local row erow); one output each
    const int ecol = tid >> 5;        // 0..31
    const int erow = tid & 31;        // 0..31
    const float sc_e = scales[r0 + erow];

    // ---- W rows -> bf16 fragments (held all 512 steps): 2 n-blocks x 8 kc ----
    bf16x8 wf[2][8];
    #pragma unroll
    for (int nb = 0; nb < 2; nb++) {
        #pragma unroll
        for (int kc = 0; kc < 8; kc++) {
            const float* src = W + (size_t)(c0 + nb * 16 + lrow) * WIDTH + w * 256 + kc * 32 + lq * 8;
            float4 f0 = *(const float4*)src;
            float4 f1 = *(const float4*)(src + 4);
            bf16x8 v;
            v[0] = (short)f2bf(f0.x); v[1] = (short)f2bf(f0.y);
            v[2] = (short)f2bf(f0.z); v[3] = (short)f2bf(f0.w);
            v[4] = (short)f2bf(f1.x); v[5] = (short)f2bf(f1.y);
            v[6] = (short)f2bf(f1.z); v[7] = (short)f2bf(f1.w);
            wf[nb][kc] = v;
        }
    }

    ushort* curs[2] = {cur0, cur1};

    // bias value for step 0, preloaded (subsequent steps prefetched post-arrival)
    float bvr = b[c0 + ecol];

    for (int d = 0; d < DEPTH; d++) {
        // ---- wait for step d-1 completion of OUR half (single broadcast line) ----
        if (d > 0) {
            if (tid == 0) {
                while (__hip_atomic_load(gflag, __ATOMIC_RELAXED, __HIP_MEMORY_SCOPE_AGENT) < d)
                    __builtin_amdgcn_s_sleep(1);
                (void)__hip_atomic_load(gflag, __ATOMIC_ACQUIRE, __HIP_MEMORY_SCOPE_AGENT);
            }
            __syncthreads();
        }

        const ushort* cin  = curs[d & 1];
        ushort*       cout = curs[(d + 1) & 1];
        const float bv = bvr;

        // ---- MFMA over this wave's 256-k slice; only our 2 m-blocks (32 rows) ----
        f32x4 acc[2][2];
        #pragma unroll
        for (int i = 0; i < 2; i++)
            #pragma unroll
            for (int nb = 0; nb < 2; nb++)
                acc[i][nb] = (f32x4){0.f, 0.f, 0.f, 0.f};

        const ushort* abase = cin + (size_t)w * 16384 + ((size_t)lq * 16 + lrow) * 8;
        bf16x8 afA[2], afB[2];
        #pragma unroll
        for (int i = 0; i < 2; i++)
            afA[i] = *(const bf16x8*)(abase + (size_t)(mb0 + i) * 512);

        #pragma unroll
        for (int kc = 0; kc < 8; kc += 2) {
            #pragma unroll
            for (int i = 0; i < 2; i++)
                afB[i] = *(const bf16x8*)(abase + ((size_t)(kc + 1) * 4 + mb0 + i) * 512);
            #pragma unroll
            for (int i = 0; i < 2; i++) {
                acc[i][0] = __builtin_amdgcn_mfma_f32_16x16x32_bf16(afA[i], wf[0][kc], acc[i][0], 0, 0, 0);
                acc[i][1] = __builtin_amdgcn_mfma_f32_16x16x32_bf16(afA[i], wf[1][kc], acc[i][1], 0, 0, 0);
            }
            if (kc + 2 < 8) {
                #pragma unroll
                for (int i = 0; i < 2; i++)
                    afA[i] = *(const bf16x8*)(abase + ((size_t)(kc + 2) * 4 + mb0 + i) * 512);
            }
            #pragma unroll
            for (int i = 0; i < 2; i++) {
                acc[i][0] = __builtin_amdgcn_mfma_f32_16x16x32_bf16(afB[i], wf[0][kc + 1], acc[i][0], 0, 0, 0);
                acc[i][1] = __builtin_amdgcn_mfma_f32_16x16x32_bf16(afB[i], wf[1][kc + 1], acc[i][1], 0, 0, 0);
            }
        }

        // ---- wave partials. C/D: col = c0+nb*16+(lane&15), local row = i*16+lq*4+r ----
        #pragma unroll
        for (int i = 0; i < 2; i++) {
            #pragma unroll
            for (int nb = 0; nb < 2; nb++) {
                const int col   = nb * 16 + lrow;
                const int rbase = (i * 16 + lq * 4) ^ ((lrow & 7) << 2);
                *(f32x4*)&partial[w * 1024 + col * 32 + rbase] = acc[i][nb];
            }
        }
        __syncthreads();

        // ---- 16-way reduce + scale/bias/erf (one output per thread) ----
        {
            const int swz = erow ^ ((ecol & 7) << 2);
            const float* p = &partial[ecol * 32 + swz];
            float s0 = 0.f, s1 = 0.f, s2 = 0.f, s3 = 0.f;
            #pragma unroll
            for (int ww = 0; ww < 16; ww += 4) {
                s0 += p[(ww + 0) * 1024];
                s1 += p[(ww + 1) * 1024];
                s2 += p[(ww + 2) * 1024];
                s3 += p[(ww + 3) * 1024];
            }
            const float sum = (s0 + s1) + (s2 + s3);
            vals[ecol * 33 + erow] = erff(sc_e * sum + bv) * 0.015625f;   // 1/sqrt(4096)
        }
        __syncthreads();

        // ---- state stripe: 8B write-through atomics, blocked layout ----
        if (tid < 256) {
            const int ml   = tid & 31;           // local row
            const int kvl  = (tid >> 5) & 3;     // local kv (8-col group)
            const int hf   = tid >> 7;           // 4-col half
            const int cb   = kvl * 8 + hf * 4;   // local col base
            const int m    = r0 + ml;            // global row
            const int kv   = (c0 >> 3) + kvl;    // global kv
            uint64_t pack =
                 (uint64_t)f2bf(vals[(cb + 0) * 33 + ml])
               | ((uint64_t)f2bf(vals[(cb + 1) * 33 + ml]) << 16)
               | ((uint64_t)f2bf(vals[(cb + 2) * 33 + ml]) << 32)
               | ((uint64_t)f2bf(vals[(cb + 3) * 33 + ml]) << 48);
            int unit = ((kv >> 2) * 4 + (m >> 4)) * 64 + (kv & 3) * 16 + (m & 15);
            uint64_t* dst = (uint64_t*)(cout + (size_t)unit * 8 + hf * 4);
            __hip_atomic_store(dst, pack, __ATOMIC_RELAXED, __HIP_MEMORY_SCOPE_AGENT);
        }

        // ---- arrival: state stores drained by the barrier; last arriver publishes ----
        __syncthreads();   // per-wave vmcnt drained -> all WG state stores complete
        if (tid == 0) {
            int old = __hip_atomic_fetch_add(ctr, 1, __ATOMIC_ACQ_REL, __HIP_MEMORY_SCOPE_AGENT);
            if (old == NGRP * (d + 1) - 1)
                __hip_atomic_store(gflag, d + 1, __ATOMIC_RELEASE, __HIP_MEMORY_SCOPE_AGENT);
        }

        // ---- next-step bias prefetch (off critical path) ----
        if (d + 1 < DEPTH)
            bvr = b[(size_t)(d + 1) * WIDTH + c0 + ecol];

        // ---- history: off the critical path (drains under next gate) ----
        const int h = d - (DEPTH - NHIST);
        if (h >= 0 && tid < 512) {
            const int ml = tid >> 4;             // local row 0..31
            const int c  = (tid & 15) * 2;       // local col pair
            union { uint64_t u; float f[2]; } p;
            p.f[0] = vals[(c + 0) * 33 + ml];
            p.f[1] = vals[(c + 1) * 33 + ml];
            uint64_t* dst = (uint64_t*)(out + ((size_t)(r0 + ml) * NHIST + h) * WIDTH + c0 + c);
            __hip_atomic_store(dst, p.u, __ATOMIC_RELAXED, __HIP_MEMORY_SCOPE_AGENT);
        }
        // vals/partial reuse at step d+1 is guarded by that step's syncthreads.
    }
}

extern "C" void kernel_launch(void* const* d_in, const int* in_sizes, int n_in,
                              void* d_out, int out_size, void* d_ws, size_t ws_size,
                              hipStream_t stream) {
    const float* x      = (const float*)d_in[0];
    const float* biases = (const float*)d_in[1];
    const float* W      = (const float*)d_in[2];
    const float* W_bias = (const float*)d_in[3];
    const float* scales = (const float*)d_in[4];
    float* out = (float*)d_out;

    char* ws = (char*)d_ws;
    float*  b    = (float*)ws;                                    // 8 MB
    ushort* cur0 = (ushort*)(ws + ((size_t)8 << 20));             // 512 KB
    ushort* cur1 = (ushort*)(ws + ((size_t)8 << 20) + (512 << 10));
    int*    flags = (int*)(ws + ((size_t)9 << 20));               // 32 KB (ctrs+gflags)

    init_curr_kernel<<<128, 256, 0, stream>>>(x, cur0);
    zero_flags_kernel<<<32, 256, 0, stream>>>(flags);
    bias_gemm_kernel<<<dim3(64, 8), 256, 0, stream>>>(biases, W_bias, b);

    void* args[] = {(void*)&W, (void*)&scales, (void*)&b, (void*)&out,
                    (void*)&cur0, (void*)&cur1, (void*)&flags};
    hipLaunchCooperativeKernel((const void*)reservoir_kernel, dim3(NWG), dim3(NTHR),
                               args, 0, stream);
}

// Round 7
// 5569.056 us; speedup vs baseline: 1.1283x; 1.1283x over previous
//
#include <hip/hip_runtime.h>
#include <cstdint>
#include <cstddef>

#define WIDTH 4096
#define DEPTH 512
#define NHIST 20
#define NWG 256
#define NTHR 1024

typedef __attribute__((ext_vector_type(4))) float f32x4;
typedef __attribute__((ext_vector_type(8))) short bf16x8;

__device__ __forceinline__ ushort f2bf(float f) {
    uint32_t u = __float_as_uint(f);
    u += 0x7FFFu + ((u >> 16) & 1u);   // round-to-nearest-even
    return (ushort)(u >> 16);
}

// cur blocked layout: element (m, c): kv=c>>3, unit = ((kv>>2)*4 + (m>>4))*64
//   + (kv&3)*16 + (m&15); ushort offset = unit*8 + (c&7).
// -> wave-w fragment f = kc*4+mb occupies ushort offset w*16384 + f*512 +
//    (lq*16+lrow)*8: one contiguous 1KB burst per load instruction.

// ---------------- curr0 = tile(x) ------------------------------------------
__global__ __launch_bounds__(256) void init_curr_kernel(const float* __restrict__ x,
                                                        ushort* __restrict__ cur) {
    int g = blockIdx.x * 256 + threadIdx.x;   // 0..32767
    int kv = g >> 6, m = g & 63;
    int unit = ((kv >> 2) * 4 + (m >> 4)) * 64 + (kv & 3) * 16 + (m & 15);
    ushort4 lo, hi;
    lo.x = f2bf(x[kv * 8 + 0]); lo.y = f2bf(x[kv * 8 + 1]);
    lo.z = f2bf(x[kv * 8 + 2]); lo.w = f2bf(x[kv * 8 + 3]);
    hi.x = f2bf(x[kv * 8 + 4]); hi.y = f2bf(x[kv * 8 + 5]);
    hi.z = f2bf(x[kv * 8 + 6]); hi.w = f2bf(x[kv * 8 + 7]);
    ushort* dst = cur + (size_t)unit * 8;
    *(ushort4*)dst = lo;
    *(ushort4*)(dst + 4) = hi;
}

// ---------------- zero flags + gflags ---------------------------------------
__global__ __launch_bounds__(256) void zero_flags_kernel(int* __restrict__ flags) {
    flags[blockIdx.x * 256 + threadIdx.x] = 0;   // grid 32 -> 8192 ints
}

// ---------------- bias GEMM, fp32 vector ALU --------------------------------
__global__ __launch_bounds__(256) void bias_gemm_kernel(const float* __restrict__ A,
                                                        const float* __restrict__ B,
                                                        float* __restrict__ C) {
    __shared__ float As[64][36];
    __shared__ float Bs[64][36];
    const int bm = blockIdx.y;
    const int bn = blockIdx.x;
    const int t  = threadIdx.x;
    const int tx = t & 15, ty = t >> 4;
    const int lr = t >> 3;
    const int lc = (t & 7) * 4;

    float acc[4][4] = {};
    for (int k0 = 0; k0 < WIDTH; k0 += 32) {
        float4 a0 = *(const float4*)&A[(size_t)(bm * 64 + lr) * WIDTH + k0 + lc];
        float4 a1 = *(const float4*)&A[(size_t)(bm * 64 + lr + 32) * WIDTH + k0 + lc];
        float4 b0 = *(const float4*)&B[(size_t)(bn * 64 + lr) * WIDTH + k0 + lc];
        float4 b1 = *(const float4*)&B[(size_t)(bn * 64 + lr + 32) * WIDTH + k0 + lc];
        __syncthreads();
        *(float4*)&As[lr][lc] = a0;  *(float4*)&As[lr + 32][lc] = a1;
        *(float4*)&Bs[lr][lc] = b0;  *(float4*)&Bs[lr + 32][lc] = b1;
        __syncthreads();
        #pragma unroll
        for (int k = 0; k < 32; k += 4) {
            float4 av[4], bv[4];
            #pragma unroll
            for (int mi = 0; mi < 4; mi++) av[mi] = *(const float4*)&As[ty * 4 + mi][k];
            #pragma unroll
            for (int ni = 0; ni < 4; ni++) bv[ni] = *(const float4*)&Bs[tx * 4 + ni][k];
            #pragma unroll
            for (int mi = 0; mi < 4; mi++)
                #pragma unroll
                for (int ni = 0; ni < 4; ni++)
                    acc[mi][ni] += av[mi].x * bv[ni].x + av[mi].y * bv[ni].y +
                                   av[mi].z * bv[ni].z + av[mi].w * bv[ni].w;
        }
    }
    #pragma unroll
    for (int mi = 0; mi < 4; mi++) {
        float4 v = make_float4(acc[mi][0], acc[mi][1], acc[mi][2], acc[mi][3]);
        *(float4*)&C[(size_t)(bm * 64 + ty * 4 + mi) * WIDTH + bn * 64 + tx * 4] = v;
    }
}

// ---------------- persistent reservoir: 256 WGs x 1024 thr ------------------
// 32x32 output tile per WG: WG t owns cols [(t>>1)*32, +32), rows (t&1)*32..+32.
// Rows are independent recurrences -> halves (t&1) are disjoint sync domains.
// Barrier per half (r1/r5 structure, verified floor across r2/r3/r4/r6
// alternatives): per-WG flag stores on 64B-spaced lines -> per-half collector
// wave sweeps its 128 flags -> per-half gflag broadcast -> tid0-only pollers.
// New in r7: 8-deep A-fragment load window. Every step the agent-scope acquire
// cold-starts L2, so all state reads are LLC-latency; the old 2-4-deep dbuf
// left each wave latency-bound (~16/3 x 900cy). Issue 8 loads at wake, roll
// use-2/reload-2 -> A-phase becomes MFMA-throughput-bound.
__global__ __launch_bounds__(NTHR, 4) void reservoir_kernel(
    const float* __restrict__ W,
    const float* __restrict__ scales,
    const float* __restrict__ b,      // [512][4096] fp32
    float* __restrict__ out,          // [64][20][4096] fp32
    ushort* __restrict__ cur0,
    ushort* __restrict__ cur1,
    int* __restrict__ flags)          // [256] stride 16 ints; gflags at +4096, +4128
{
    // partial: [wave16][col32][row32] fp32, XOR-swizzled rows:
    //   float idx = w*1024 + c*32 + (r ^ ((c&7)<<2))  -> conflict-free b128
    __shared__ float partial[16 * 32 * 32];   // 64 KB
    __shared__ float vals[32 * 33];           // [col][row] padded 33

    const int tid  = threadIdx.x;
    const int w    = tid >> 6;
    const int lane = tid & 63;
    const int lrow = lane & 15;
    const int lq   = lane >> 4;
    const int t    = blockIdx.x;
    const int half = t & 1;
    const int c0   = (t >> 1) * 32;   // global col base
    const int r0   = half * 32;       // global row (scale) base
    const int mb0  = half * 2;        // m-block base in blocked state layout
    int* gflag = flags + 4096 + half * 32;   // per-half broadcast lines, 128B apart

    // epilogue mapping: thread -> (local col ecol, local row erow); one output each
    const int ecol = tid >> 5;        // 0..31
    const int erow = tid & 31;        // 0..31
    const float sc_e = scales[r0 + erow];

    // ---- W rows -> bf16 fragments (held all 512 steps): 2 n-blocks x 8 kc ----
    bf16x8 wf[2][8];
    #pragma unroll
    for (int nb = 0; nb < 2; nb++) {
        #pragma unroll
        for (int kc = 0; kc < 8; kc++) {
            const float* src = W + (size_t)(c0 + nb * 16 + lrow) * WIDTH + w * 256 + kc * 32 + lq * 8;
            float4 f0 = *(const float4*)src;
            float4 f1 = *(const float4*)(src + 4);
            bf16x8 v;
            v[0] = (short)f2bf(f0.x); v[1] = (short)f2bf(f0.y);
            v[2] = (short)f2bf(f0.z); v[3] = (short)f2bf(f0.w);
            v[4] = (short)f2bf(f1.x); v[5] = (short)f2bf(f1.y);
            v[6] = (short)f2bf(f1.z); v[7] = (short)f2bf(f1.w);
            wf[nb][kc] = v;
        }
    }

    ushort* curs[2] = {cur0, cur1};

    // bias value for step 0, preloaded (subsequent steps prefetched post-release)
    float bvr = b[c0 + ecol];

    for (int d = 0; d < DEPTH; d++) {
        // ---- wait for step d-1 completion of OUR half (single broadcast line) ----
        if (d > 0) {
            if (tid == 0) {
                while (__hip_atomic_load(gflag, __ATOMIC_RELAXED, __HIP_MEMORY_SCOPE_AGENT) < d)
                    __builtin_amdgcn_s_sleep(1);
                (void)__hip_atomic_load(gflag, __ATOMIC_ACQUIRE, __HIP_MEMORY_SCOPE_AGENT);
            }
            __syncthreads();
        }

        const ushort* cin  = curs[d & 1];
        ushort*       cout = curs[(d + 1) & 1];
        const float bv = bvr;

        // ---- MFMA over this wave's 256-k slice; 8-deep rolling load window ----
        f32x4 acc[2][2];
        #pragma unroll
        for (int i = 0; i < 2; i++)
            #pragma unroll
            for (int nb = 0; nb < 2; nb++)
                acc[i][nb] = (f32x4){0.f, 0.f, 0.f, 0.f};

        const ushort* abase = cin + (size_t)w * 16384 + ((size_t)lq * 16 + lrow) * 8;

        bf16x8 af[8];
        #pragma unroll
        for (int j = 0; j < 4; j++) {          // fragments for kc = 0..3, 8 loads in flight
            af[2 * j]     = *(const bf16x8*)(abase + ((size_t)j * 4 + mb0) * 512);
            af[2 * j + 1] = *(const bf16x8*)(abase + ((size_t)j * 4 + mb0 + 1) * 512);
        }

        #pragma unroll
        for (int kc = 0; kc < 8; kc++) {
            const int s = (kc & 3) * 2;        // compile-time after unroll
            acc[0][0] = __builtin_amdgcn_mfma_f32_16x16x32_bf16(af[s],     wf[0][kc], acc[0][0], 0, 0, 0);
            acc[0][1] = __builtin_amdgcn_mfma_f32_16x16x32_bf16(af[s],     wf[1][kc], acc[0][1], 0, 0, 0);
            acc[1][0] = __builtin_amdgcn_mfma_f32_16x16x32_bf16(af[s + 1], wf[0][kc], acc[1][0], 0, 0, 0);
            acc[1][1] = __builtin_amdgcn_mfma_f32_16x16x32_bf16(af[s + 1], wf[1][kc], acc[1][1], 0, 0, 0);
            if (kc < 4) {                      // refill window for kc+4
                af[s]     = *(const bf16x8*)(abase + ((size_t)(kc + 4) * 4 + mb0) * 512);
                af[s + 1] = *(const bf16x8*)(abase + ((size_t)(kc + 4) * 4 + mb0 + 1) * 512);
            }
        }

        // ---- wave partials. C/D: col = c0+nb*16+(lane&15), local row = i*16+lq*4+r ----
        #pragma unroll
        for (int i = 0; i < 2; i++) {
            #pragma unroll
            for (int nb = 0; nb < 2; nb++) {
                const int col   = nb * 16 + lrow;
                const int rbase = (i * 16 + lq * 4) ^ ((lrow & 7) << 2);
                *(f32x4*)&partial[w * 1024 + col * 32 + rbase] = acc[i][nb];
            }
        }
        __syncthreads();

        // ---- 16-way reduce + scale/bias/erf (one output per thread) ----
        {
            const int swz = erow ^ ((ecol & 7) << 2);
            const float* p = &partial[ecol * 32 + swz];
            float s0 = 0.f, s1 = 0.f, s2 = 0.f, s3 = 0.f;
            #pragma unroll
            for (int ww = 0; ww < 16; ww += 4) {
                s0 += p[(ww + 0) * 1024];
                s1 += p[(ww + 1) * 1024];
                s2 += p[(ww + 2) * 1024];
                s3 += p[(ww + 3) * 1024];
            }
            const float sum = (s0 + s1) + (s2 + s3);
            vals[ecol * 33 + erow] = erff(sc_e * sum + bv) * 0.015625f;   // 1/sqrt(4096)
        }
        __syncthreads();

        // ---- state stripe: 8B write-through atomics, blocked layout ----
        if (tid < 256) {
            const int ml   = tid & 31;           // local row
            const int kvl  = (tid >> 5) & 3;     // local kv (8-col group)
            const int hf   = tid >> 7;           // 4-col half
            const int cb   = kvl * 8 + hf * 4;   // local col base
            const int m    = r0 + ml;            // global row
            const int kv   = (c0 >> 3) + kvl;    // global kv
            uint64_t pack =
                 (uint64_t)f2bf(vals[(cb + 0) * 33 + ml])
               | ((uint64_t)f2bf(vals[(cb + 1) * 33 + ml]) << 16)
               | ((uint64_t)f2bf(vals[(cb + 2) * 33 + ml]) << 32)
               | ((uint64_t)f2bf(vals[(cb + 3) * 33 + ml]) << 48);
            int unit = ((kv >> 2) * 4 + (m >> 4)) * 64 + (kv & 3) * 16 + (m & 15);
            uint64_t* dst = (uint64_t*)(cout + (size_t)unit * 8 + hf * 4);
            __hip_atomic_store(dst, pack, __ATOMIC_RELAXED, __HIP_MEMORY_SCOPE_AGENT);
        }

        // ---- release: state stores drained by the barrier; own flag, own line ----
        __syncthreads();   // per-wave vmcnt drained -> all WG state stores complete
        if (tid == 0)
            __hip_atomic_store(flags + t * 16, d + 1,
                               __ATOMIC_RELEASE, __HIP_MEMORY_SCOPE_AGENT);

        // ---- next-step bias prefetch (off critical path) ----
        if (d + 1 < DEPTH)
            bvr = b[(size_t)(d + 1) * WIDTH + c0 + ecol];

        // ---- history: off the critical path (drains under next gate) ----
        const int h = d - (DEPTH - NHIST);
        if (h >= 0 && tid < 512) {
            const int ml = tid >> 4;             // local row 0..31
            const int c  = (tid & 15) * 2;       // local col pair
            union { uint64_t u; float f[2]; } p;
            p.f[0] = vals[(c + 0) * 33 + ml];
            p.f[1] = vals[(c + 1) * 33 + ml];
            uint64_t* dst = (uint64_t*)(out + ((size_t)(r0 + ml) * NHIST + h) * WIDTH + c0 + c);
            __hip_atomic_store(dst, p.u, __ATOMIC_RELAXED, __HIP_MEMORY_SCOPE_AGENT);
        }

        // ---- per-half collector: WG 'half' wave0 sweeps its 128 flags ----
        if (t == half && w == 0) {
            for (;;) {
                bool ok = true;
                #pragma unroll
                for (int q = 0; q < 2; q++) {
                    // half's WG ids: 2*j + half, j = lane + q*64
                    int v = __hip_atomic_load(flags + ((lane + q * 64) * 2 + half) * 16,
                                              __ATOMIC_RELAXED, __HIP_MEMORY_SCOPE_AGENT);
                    ok = ok && (v >= d + 1);
                }
                if (__all(ok)) break;
                __builtin_amdgcn_s_sleep(1);
            }
            if (lane == 0) {
                (void)__hip_atomic_load(flags, __ATOMIC_ACQUIRE, __HIP_MEMORY_SCOPE_AGENT);
                __hip_atomic_store(gflag, d + 1, __ATOMIC_RELEASE, __HIP_MEMORY_SCOPE_AGENT);
            }
        }
        // vals/partial reuse at step d+1 is guarded by that step's syncthreads.
    }
}

extern "C" void kernel_launch(void* const* d_in, const int* in_sizes, int n_in,
                              void* d_out, int out_size, void* d_ws, size_t ws_size,
                              hipStream_t stream) {
    const float* x      = (const float*)d_in[0];
    const float* biases = (const float*)d_in[1];
    const float* W      = (const float*)d_in[2];
    const float* W_bias = (const float*)d_in[3];
    const float* scales = (const float*)d_in[4];
    float* out = (float*)d_out;

    char* ws = (char*)d_ws;
    float*  b    = (float*)ws;                                    // 8 MB
    ushort* cur0 = (ushort*)(ws + ((size_t)8 << 20));             // 512 KB
    ushort* cur1 = (ushort*)(ws + ((size_t)8 << 20) + (512 << 10));
    int*    flags = (int*)(ws + ((size_t)9 << 20));               // 32 KB (flags+gflags)

    init_curr_kernel<<<128, 256, 0, stream>>>(x, cur0);
    zero_flags_kernel<<<32, 256, 0, stream>>>(flags);
    bias_gemm_kernel<<<dim3(64, 8), 256, 0, stream>>>(biases, W_bias, b);

    void* args[] = {(void*)&W, (void*)&scales, (void*)&b, (void*)&out,
                    (void*)&cur0, (void*)&cur1, (void*)&flags};
    hipLaunchCooperativeKernel((const void*)reservoir_kernel, dim3(NWG), dim3(NTHR),
                               args, 0, stream);
}

// Round 8
// 4764.279 us; speedup vs baseline: 1.3188x; 1.1689x over previous
//
#include <hip/hip_runtime.h>
#include <cstdint>
#include <cstddef>

#define WIDTH 4096
#define DEPTH 512
#define NHIST 20
#define NWG 256
#define NTHR 1024

typedef __attribute__((ext_vector_type(4))) float f32x4;
typedef __attribute__((ext_vector_type(8))) short bf16x8;

__device__ __forceinline__ ushort f2bf(float f) {
    uint32_t u = __float_as_uint(f);
    u += 0x7FFFu + ((u >> 16) & 1u);   // round-to-nearest-even
    return (ushort)(u >> 16);
}

// cur blocked layout: element (m, c): kv=c>>3, unit = ((kv>>2)*4 + (m>>4))*64
//   + (kv&3)*16 + (m&15); ushort offset = unit*8 + (c&7).
// -> wave-w fragment f = kc*4+mb occupies ushort offset w*16384 + f*512 +
//    (lq*16+lrow)*8: one contiguous 1KB burst per load instruction.
// Half h owns mb blocks {2h,2h+1}: per kv-quad, halves occupy alternating
// contiguous 2KB blocks -> cacheline-disjoint between halves.

// ---------------- curr0 = tile(x) ------------------------------------------
__global__ __launch_bounds__(256) void init_curr_kernel(const float* __restrict__ x,
                                                        ushort* __restrict__ cur) {
    int g = blockIdx.x * 256 + threadIdx.x;   // 0..32767
    int kv = g >> 6, m = g & 63;
    int unit = ((kv >> 2) * 4 + (m >> 4)) * 64 + (kv & 3) * 16 + (m & 15);
    ushort4 lo, hi;
    lo.x = f2bf(x[kv * 8 + 0]); lo.y = f2bf(x[kv * 8 + 1]);
    lo.z = f2bf(x[kv * 8 + 2]); lo.w = f2bf(x[kv * 8 + 3]);
    hi.x = f2bf(x[kv * 8 + 4]); hi.y = f2bf(x[kv * 8 + 5]);
    hi.z = f2bf(x[kv * 8 + 6]); hi.w = f2bf(x[kv * 8 + 7]);
    ushort* dst = cur + (size_t)unit * 8;
    *(ushort4*)dst = lo;
    *(ushort4*)(dst + 4) = hi;
}

// ---------------- zero flags + gflags ---------------------------------------
__global__ __launch_bounds__(256) void zero_flags_kernel(int* __restrict__ flags) {
    flags[blockIdx.x * 256 + threadIdx.x] = 0;   // grid 32 -> 8192 ints
}

// ---------------- bias GEMM, fp32 vector ALU --------------------------------
__global__ __launch_bounds__(256) void bias_gemm_kernel(const float* __restrict__ A,
                                                        const float* __restrict__ B,
                                                        float* __restrict__ C) {
    __shared__ float As[64][36];
    __shared__ float Bs[64][36];
    const int bm = blockIdx.y;
    const int bn = blockIdx.x;
    const int t  = threadIdx.x;
    const int tx = t & 15, ty = t >> 4;
    const int lr = t >> 3;
    const int lc = (t & 7) * 4;

    float acc[4][4] = {};
    for (int k0 = 0; k0 < WIDTH; k0 += 32) {
        float4 a0 = *(const float4*)&A[(size_t)(bm * 64 + lr) * WIDTH + k0 + lc];
        float4 a1 = *(const float4*)&A[(size_t)(bm * 64 + lr + 32) * WIDTH + k0 + lc];
        float4 b0 = *(const float4*)&B[(size_t)(bn * 64 + lr) * WIDTH + k0 + lc];
        float4 b1 = *(const float4*)&B[(size_t)(bn * 64 + lr + 32) * WIDTH + k0 + lc];
        __syncthreads();
        *(float4*)&As[lr][lc] = a0;  *(float4*)&As[lr + 32][lc] = a1;
        *(float4*)&Bs[lr][lc] = b0;  *(float4*)&Bs[lr + 32][lc] = b1;
        __syncthreads();
        #pragma unroll
        for (int k = 0; k < 32; k += 4) {
            float4 av[4], bv[4];
            #pragma unroll
            for (int mi = 0; mi < 4; mi++) av[mi] = *(const float4*)&As[ty * 4 + mi][k];
            #pragma unroll
            for (int ni = 0; ni < 4; ni++) bv[ni] = *(const float4*)&Bs[tx * 4 + ni][k];
            #pragma unroll
            for (int mi = 0; mi < 4; mi++)
                #pragma unroll
                for (int ni = 0; ni < 4; ni++)
                    acc[mi][ni] += av[mi].x * bv[ni].x + av[mi].y * bv[ni].y +
                                   av[mi].z * bv[ni].z + av[mi].w * bv[ni].w;
        }
    }
    #pragma unroll
    for (int mi = 0; mi < 4; mi++) {
        float4 v = make_float4(acc[mi][0], acc[mi][1], acc[mi][2], acc[mi][3]);
        *(float4*)&C[(size_t)(bm * 64 + ty * 4 + mi) * WIDTH + bn * 64 + tx * 4] = v;
    }
}

// ---------------- persistent reservoir: 256 WGs x 1024 thr ------------------
// 32x32 output tile per WG: WG t owns cols [(t>>1)*32, +32), rows (t&1)*32..+32.
// Barrier per half (r1/r5/r7 structure, verified floor): per-WG flag stores ->
// per-half collector wave -> per-half gflag broadcast -> tid0-only pollers.
// New in r8: 4-deep state buffer rotation + acquire/inv only at d%4==0.
// Staleness invariant: this CU's L1/XCD's L2 can hold lines of buffer s%4 only
// from our own reads at step s-4 (same-half WGs are barrier-synced and read
// the same fresh buffer; other-half rows are in disjoint 2KB blocks; flag
// atomics bypass caches; W is in regs; b is immutable). So one buffer_inv in
// (s-4, s] covers -- the acquire at d%4==0. On the 3 inv-free steps the 32
// same-half WGs of an XCD share the 256KB stripe through L2 instead of each
// re-pulling it from the Infinity Cache. Inv issued BEFORE the poll to hide
// its latency. Correctness does not depend on WG->XCD mapping.
__global__ __launch_bounds__(NTHR, 4) void reservoir_kernel(
    const float* __restrict__ W,
    const float* __restrict__ scales,
    const float* __restrict__ b,      // [512][4096] fp32
    float* __restrict__ out,          // [64][20][4096] fp32
    ushort* __restrict__ cur,         // 4 x 512KB buffers, contiguous
    int* __restrict__ flags)          // [256] stride 16 ints; gflags at +4096, +4128
{
    // partial: [wave16][col32][row32] fp32, XOR-swizzled rows:
    //   float idx = w*1024 + c*32 + (r ^ ((c&7)<<2))  -> conflict-free b128
    __shared__ float partial[16 * 32 * 32];   // 64 KB
    __shared__ float vals[32 * 33];           // [col][row] padded 33

    const int tid  = threadIdx.x;
    const int w    = tid >> 6;
    const int lane = tid & 63;
    const int lrow = lane & 15;
    const int lq   = lane >> 4;
    const int t    = blockIdx.x;
    const int half = t & 1;
    const int c0   = (t >> 1) * 32;   // global col base
    const int r0   = half * 32;       // global row (scale) base
    const int mb0  = half * 2;        // m-block base in blocked state layout
    int* gflag = flags + 4096 + half * 32;   // per-half broadcast lines, 128B apart

    // epilogue mapping: thread -> (local col ecol, local row erow); one output each
    const int ecol = tid >> 5;        // 0..31
    const int erow = tid & 31;        // 0..31
    const float sc_e = scales[r0 + erow];

    // ---- W rows -> bf16 fragments (held all 512 steps): 2 n-blocks x 8 kc ----
    bf16x8 wf[2][8];
    #pragma unroll
    for (int nb = 0; nb < 2; nb++) {
        #pragma unroll
        for (int kc = 0; kc < 8; kc++) {
            const float* src = W + (size_t)(c0 + nb * 16 + lrow) * WIDTH + w * 256 + kc * 32 + lq * 8;
            float4 f0 = *(const float4*)src;
            float4 f1 = *(const float4*)(src + 4);
            bf16x8 v;
            v[0] = (short)f2bf(f0.x); v[1] = (short)f2bf(f0.y);
            v[2] = (short)f2bf(f0.z); v[3] = (short)f2bf(f0.w);
            v[4] = (short)f2bf(f1.x); v[5] = (short)f2bf(f1.y);
            v[6] = (short)f2bf(f1.z); v[7] = (short)f2bf(f1.w);
            wf[nb][kc] = v;
        }
    }

    // bias value for step 0, preloaded (subsequent steps prefetched post-release)
    float bvr = b[c0 + ecol];

    for (int d = 0; d < DEPTH; d++) {
        // ---- wait for step d-1 completion of OUR half (single broadcast line) ----
        if (d > 0) {
            if (tid == 0) {
                if ((d & 3) == 0)   // periodic inv, fired early to hide latency
                    (void)__hip_atomic_load(gflag, __ATOMIC_ACQUIRE, __HIP_MEMORY_SCOPE_AGENT);
                while (__hip_atomic_load(gflag, __ATOMIC_RELAXED, __HIP_MEMORY_SCOPE_AGENT) < d)
                    __builtin_amdgcn_s_sleep(1);
            }
            __syncthreads();
        }

        const ushort* cin  = cur + ((size_t)(d & 3) << 18);        // 512KB buffers
        ushort*       cout = cur + ((size_t)((d + 1) & 3) << 18);
        const float bv = bvr;

        // ---- MFMA over this wave's 256-k slice; 8-deep rolling load window ----
        f32x4 acc[2][2];
        #pragma unroll
        for (int i = 0; i < 2; i++)
            #pragma unroll
            for (int nb = 0; nb < 2; nb++)
                acc[i][nb] = (f32x4){0.f, 0.f, 0.f, 0.f};

        const ushort* abase = cin + (size_t)w * 16384 + ((size_t)lq * 16 + lrow) * 8;

        bf16x8 af[8];
        #pragma unroll
        for (int j = 0; j < 4; j++) {          // fragments for kc = 0..3, 8 loads in flight
            af[2 * j]     = *(const bf16x8*)(abase + ((size_t)j * 4 + mb0) * 512);
            af[2 * j + 1] = *(const bf16x8*)(abase + ((size_t)j * 4 + mb0 + 1) * 512);
        }

        #pragma unroll
        for (int kc = 0; kc < 8; kc++) {
            const int s = (kc & 3) * 2;        // compile-time after unroll
            acc[0][0] = __builtin_amdgcn_mfma_f32_16x16x32_bf16(af[s],     wf[0][kc], acc[0][0], 0, 0, 0);
            acc[0][1] = __builtin_amdgcn_mfma_f32_16x16x32_bf16(af[s],     wf[1][kc], acc[0][1], 0, 0, 0);
            acc[1][0] = __builtin_amdgcn_mfma_f32_16x16x32_bf16(af[s + 1], wf[0][kc], acc[1][0], 0, 0, 0);
            acc[1][1] = __builtin_amdgcn_mfma_f32_16x16x32_bf16(af[s + 1], wf[1][kc], acc[1][1], 0, 0, 0);
            if (kc < 4) {                      // refill window for kc+4
                af[s]     = *(const bf16x8*)(abase + ((size_t)(kc + 4) * 4 + mb0) * 512);
                af[s + 1] = *(const bf16x8*)(abase + ((size_t)(kc + 4) * 4 + mb0 + 1) * 512);
            }
        }

        // ---- wave partials. C/D: col = c0+nb*16+(lane&15), local row = i*16+lq*4+r ----
        #pragma unroll
        for (int i = 0; i < 2; i++) {
            #pragma unroll
            for (int nb = 0; nb < 2; nb++) {
                const int col   = nb * 16 + lrow;
                const int rbase = (i * 16 + lq * 4) ^ ((lrow & 7) << 2);
                *(f32x4*)&partial[w * 1024 + col * 32 + rbase] = acc[i][nb];
            }
        }
        __syncthreads();

        // ---- 16-way reduce + scale/bias/erf (one output per thread) ----
        {
            const int swz = erow ^ ((ecol & 7) << 2);
            const float* p = &partial[ecol * 32 + swz];
            float s0 = 0.f, s1 = 0.f, s2 = 0.f, s3 = 0.f;
            #pragma unroll
            for (int ww = 0; ww < 16; ww += 4) {
                s0 += p[(ww + 0) * 1024];
                s1 += p[(ww + 1) * 1024];
                s2 += p[(ww + 2) * 1024];
                s3 += p[(ww + 3) * 1024];
            }
            const float sum = (s0 + s1) + (s2 + s3);
            vals[ecol * 33 + erow] = erff(sc_e * sum + bv) * 0.015625f;   // 1/sqrt(4096)
        }
        __syncthreads();

        // ---- state stripe: 8B write-through atomics, blocked layout ----
        if (tid < 256) {
            const int ml   = tid & 31;           // local row
            const int kvl  = (tid >> 5) & 3;     // local kv (8-col group)
            const int hf   = tid >> 7;           // 4-col half
            const int cb   = kvl * 8 + hf * 4;   // local col base
            const int m    = r0 + ml;            // global row
            const int kv   = (c0 >> 3) + kvl;    // global kv
            uint64_t pack =
                 (uint64_t)f2bf(vals[(cb + 0) * 33 + ml])
               | ((uint64_t)f2bf(vals[(cb + 1) * 33 + ml]) << 16)
               | ((uint64_t)f2bf(vals[(cb + 2) * 33 + ml]) << 32)
               | ((uint64_t)f2bf(vals[(cb + 3) * 33 + ml]) << 48);
            int unit = ((kv >> 2) * 4 + (m >> 4)) * 64 + (kv & 3) * 16 + (m & 15);
            uint64_t* dst = (uint64_t*)(cout + (size_t)unit * 8 + hf * 4);
            __hip_atomic_store(dst, pack, __ATOMIC_RELAXED, __HIP_MEMORY_SCOPE_AGENT);
        }

        // ---- release: state stores drained by the barrier; own flag, own line ----
        __syncthreads();   // per-wave vmcnt drained -> all WG state stores complete
        if (tid == 0)
            __hip_atomic_store(flags + t * 16, d + 1,
                               __ATOMIC_RELEASE, __HIP_MEMORY_SCOPE_AGENT);

        // ---- next-step bias prefetch (off critical path) ----
        if (d + 1 < DEPTH)
            bvr = b[(size_t)(d + 1) * WIDTH + c0 + ecol];

        // ---- history: off the critical path (drains under next gate) ----
        const int h = d - (DEPTH - NHIST);
        if (h >= 0 && tid < 512) {
            const int ml = tid >> 4;             // local row 0..31
            const int c  = (tid & 15) * 2;       // local col pair
            union { uint64_t u; float f[2]; } p;
            p.f[0] = vals[(c + 0) * 33 + ml];
            p.f[1] = vals[(c + 1) * 33 + ml];
            uint64_t* dst = (uint64_t*)(out + ((size_t)(r0 + ml) * NHIST + h) * WIDTH + c0 + c);
            __hip_atomic_store(dst, p.u, __ATOMIC_RELAXED, __HIP_MEMORY_SCOPE_AGENT);
        }

        // ---- per-half collector: WG 'half' wave0 sweeps its 128 flags ----
        if (t == half && w == 0) {
            for (;;) {
                bool ok = true;
                #pragma unroll
                for (int q = 0; q < 2; q++) {
                    // half's WG ids: 2*j + half, j = lane + q*64
                    int v = __hip_atomic_load(flags + ((lane + q * 64) * 2 + half) * 16,
                                              __ATOMIC_RELAXED, __HIP_MEMORY_SCOPE_AGENT);
                    ok = ok && (v >= d + 1);
                }
                if (__all(ok)) break;
                __builtin_amdgcn_s_sleep(1);
            }
            if (lane == 0) {
                (void)__hip_atomic_load(flags, __ATOMIC_ACQUIRE, __HIP_MEMORY_SCOPE_AGENT);
                __hip_atomic_store(gflag, d + 1, __ATOMIC_RELEASE, __HIP_MEMORY_SCOPE_AGENT);
            }
        }
        // vals/partial reuse at step d+1 is guarded by that step's syncthreads.
    }
}

extern "C" void kernel_launch(void* const* d_in, const int* in_sizes, int n_in,
                              void* d_out, int out_size, void* d_ws, size_t ws_size,
                              hipStream_t stream) {
    const float* x      = (const float*)d_in[0];
    const float* biases = (const float*)d_in[1];
    const float* W      = (const float*)d_in[2];
    const float* W_bias = (const float*)d_in[3];
    const float* scales = (const float*)d_in[4];
    float* out = (float*)d_out;

    char* ws = (char*)d_ws;
    float*  b    = (float*)ws;                                    // 8 MB
    ushort* cur  = (ushort*)(ws + ((size_t)8 << 20));             // 4 x 512 KB
    int*    flags = (int*)(ws + ((size_t)10 << 20));              // 32 KB (flags+gflags)

    init_curr_kernel<<<128, 256, 0, stream>>>(x, cur);
    zero_flags_kernel<<<32, 256, 0, stream>>>(flags);
    bias_gemm_kernel<<<dim3(64, 8), 256, 0, stream>>>(biases, W_bias, b);

    void* args[] = {(void*)&W, (void*)&scales, (void*)&b, (void*)&out,
                    (void*)&cur, (void*)&flags};
    hipLaunchCooperativeKernel((const void*)reservoir_kernel, dim3(NWG), dim3(NTHR),
                               args, 0, stream);
}